// Round 1
// 2098.800 us; speedup vs baseline: 1.1304x; 1.1304x over previous
//
#include <hip/hip_runtime.h>
#include <hip/hip_bf16.h>
#include <cstddef>
#include <cstdint>

namespace {

constexpr int B = 2048, T = 128, F = 128, H = 512, L = 8, KW = 10;
constexpr int GATES = 2064;
constexpr int NG = 2048;    // gate columns (permuted)
constexpr int KIN = 640;    // F + H
constexpr int HS = 85;      // H // 6
constexpr int RC = H * KW;  // 5120
constexpr int KS = 8;       // conv split-K slices
constexpr int NROW = 144;   // Bs rows per tile: 128 gates + 16 logit cols

typedef __attribute__((ext_vector_type(8))) short short8;
typedef __attribute__((ext_vector_type(4))) float f32x4;
typedef unsigned long long ull;

__device__ __forceinline__ float fsigmoid_(float x) {
    return __builtin_amdgcn_rcpf(1.0f + __expf(-x));
}
__device__ __forceinline__ float ftanh_(float x) {
    return 1.0f - 2.0f * __builtin_amdgcn_rcpf(1.0f + __expf(2.0f * x));
}

__device__ __forceinline__ void gl_lds16(const void* g, void* l) {
    __builtin_amdgcn_global_load_lds(
        (const __attribute__((address_space(1))) unsigned int*)g,
        (__attribute__((address_space(3))) unsigned int*)l,
        16, 0, 0);
}

__device__ __forceinline__ ull h_atomic_load(const void* p) {
    return __hip_atomic_load((const ull*)p, __ATOMIC_RELAXED, __HIP_MEMORY_SCOPE_AGENT);
}

// ---------- prep (unchanged) ----------
__global__ __launch_bounds__(256) void prep_wgt(
    const float* __restrict__ Wk, const float* __restrict__ Wr,
    __hip_bfloat16* __restrict__ WgT)
{
    __shared__ float tile[64 * 65];
    const int tid = threadIdx.x;
    const int c0 = blockIdx.x * 64, k0 = blockIdx.y * 64;
#pragma unroll
    for (int rep = 0; rep < 16; ++rep) {
        int e = rep * 256 + tid;
        int kl = e >> 6, cl = e & 63;
        int col = c0 + cl;
        int nt = col >> 7, cc = col & 127;
        int n = 16 + ((cc >> 4) & 3) * 512 + nt * 32 + ((cc >> 6) & 1) * 16 + (cc & 15);
        int k = k0 + kl;
        tile[kl * 65 + cl] = (k < F) ? Wk[(size_t)k * GATES + n] : Wr[(size_t)(k - F) * GATES + n];
    }
    __syncthreads();
    const int cl = tid >> 2, q = tid & 3;
    unsigned short buf[16];
#pragma unroll
    for (int i = 0; i < 16; ++i) {
        float f = tile[(q * 16 + i) * 65 + cl];
        __hip_bfloat16 bv = __float2bfloat16(f);
        buf[i] = *(unsigned short*)&bv;
    }
    int col = c0 + cl;
    int nt = col >> 7, rin = col & 127;
    unsigned short* dst = (unsigned short*)WgT + (size_t)nt * NROW * KIN + (size_t)rin * KIN + k0 + q * 16;
    *(short8*)dst = *(short8*)&buf[0];
    *(short8*)(dst + 8) = *(short8*)&buf[8];
}

__global__ void prep_w16rep(const float* __restrict__ Wk, const float* __restrict__ Wr,
                            __hip_bfloat16* __restrict__ WgT)
{
    int idx = blockIdx.x * blockDim.x + threadIdx.x;
    if (idx >= 16 * 16 * KIN) return;
    int nt = idx / (16 * KIN);
    int rem = idx % (16 * KIN);
    int n = rem / KIN, k = rem % KIN;
    float v = (k < F) ? Wk[(size_t)k * GATES + n] : Wr[(size_t)(k - F) * GATES + n];
    WgT[(size_t)nt * NROW * KIN + (size_t)(128 + n) * KIN + k] = __float2bfloat16(v);
}

__global__ void prep_small(const float* __restrict__ Wk, const float* __restrict__ bk,
                           const float* __restrict__ Wr, const float* __restrict__ br,
                           float* __restrict__ biasg, float* __restrict__ wrowg,
                           float* __restrict__ bias16, float* __restrict__ wrow16)
{
    const int total = 2 * NG + 32;
    for (int idx = threadIdx.x; idx < total; idx += 256) {
        if (idx < NG) {
            int col = idx;
            int nt = col >> 7, cc = col & 127;
            int n = 16 + ((cc >> 4) & 3) * 512 + nt * 32 + ((cc >> 6) & 1) * 16 + (cc & 15);
            biasg[col] = bk[n] + br[n];
        } else if (idx < 2 * NG) {
            int col = idx - NG;
            int nt = col >> 7, cc = col & 127;
            int n = 16 + ((cc >> 4) & 3) * 512 + nt * 32 + ((cc >> 6) & 1) * 16 + (cc & 15);
            wrowg[col] = Wk[(size_t)F * GATES + n] + Wr[(size_t)H * GATES + n];
        } else if (idx < 2 * NG + 16) {
            int n = idx - 2 * NG;
            bias16[n] = bk[n] + br[n];
        } else {
            int n = idx - 2 * NG - 16;
            wrow16[n] = Wk[(size_t)F * GATES + n] + Wr[(size_t)H * GATES + n];
        }
    }
}

__global__ void convert_x(const float* __restrict__ x, __hip_bfloat16* __restrict__ xb) {
    int i = blockIdx.x * blockDim.x + threadIdx.x;
    size_t o = (size_t)i * 4;
    if (o >= (size_t)B * T * F) return;
    float4 v = *(const float4*)(x + o);
    xb[o + 0] = __float2bfloat16(v.x);
    xb[o + 1] = __float2bfloat16(v.y);
    xb[o + 2] = __float2bfloat16(v.z);
    xb[o + 3] = __float2bfloat16(v.w);
}

__global__ void prep_convw(const float* __restrict__ conv_w, __hip_bfloat16* __restrict__ CWb) {
    int i = blockIdx.x * blockDim.x + threadIdx.x;
    if (i >= H * RC / 4) return;
    size_t o = (size_t)i * 4;
    float4 v = *(const float4*)(conv_w + o);
    CWb[o + 0] = __float2bfloat16(v.x);
    CWb[o + 1] = __float2bfloat16(v.y);
    CWb[o + 2] = __float2bfloat16(v.z);
    CWb[o + 3] = __float2bfloat16(v.w);
}

// ---------- persistent fused step ----------
struct StepArgs {
    const __hip_bfloat16* xb;
    __hip_bfloat16* h0;
    __hip_bfloat16* h1;
    const __hip_bfloat16* WgT;
    const float* biasg;
    const float* wrowg;
    const float* bias16;
    const float* wrow16;
    const float* tme;
    __hip_bfloat16* tmp_h;
    float* tmp_ds;
    float* dist_out;
    unsigned* bar;  // per-mt-group counters, 256 B apart
};

// 256 blocks (16 mt x 16 nt, XCD-swizzled), 512 threads. M-tile 128, N-tile
// 128(+16 logit rows), BK 32, fully unrolled 20-iter k-loop, LDS double-buffer.
// cell state in registers; h exchanged via relaxed agent atomics.
// R9: (a) k-loop uses raw s_barrier + counted vmcnt (never 0 mid-loop) so the
//     3-iter-ahead h prefetch actually stays in flight across barriers;
//     (b) grid barrier replaced by per-mt-group counter (the 16 nt blocks of an
//     mt group are a closed h-communication set; groups drift independently);
//     (c) softmax-cumsum split across 256 threads (fm/im halves independent).
__global__ __launch_bounds__(512, 2) void persistent_step(StepArgs a)
{
    // abuf0 @0 (8K) | abuf1 @8192 | bbuf0 @16384 (9216) | bbuf1 @25600 -> 34816 B
    __shared__ __align__(16) char smem[34816];
    // epilogue aliases (all staging except bbuf1 dead by then):
    float* logitS = (float*)smem;                              // 128*17*4 = 8704
    float* fmimS = (float*)(smem + 8704);                      // 8192
    unsigned short* hstageS = (unsigned short*)(smem + 16896); // 8192
    float* dts = (float*)(smem + 25088);                       // 512

    const int tid = threadIdx.x;
    const int wave = tid >> 6;
    const int wr = wave >> 1, wc = wave & 1;   // wr 0..3, wc 0..1
    const int quad = (tid & 63) >> 4, m16 = tid & 15;
    const int l = blockIdx.x;
    const int nt = ((l & 7) << 1) | ((l >> 3) & 1);  // same-nt -> same XCD
    const int mt = l >> 4;
    const int m0 = mt * 128;

    // ---- per-thread staging geometry (A tile 128x32 bf16 = 8 KB; 16 B/thread)
    const int o0 = tid * 16;
    const int arow = o0 >> 6;                       // 64 B per row
    const int asl = ((((o0 >> 4) & 3) ^ ((arow >> 1) & 3)) << 3);  // k-elt offset
    const char* xbT = (const char*)a.xb + (size_t)(m0 + arow) * (T * F * 2) + asl * 2;
    const size_t hbyte = (size_t)(m0 + arow) * (H * 2) + asl * 2;
    // Bs: 144x32 bf16 = 9216 B; p0 = tid*16 (all), p1 = 8192 + tid*16 (tid<64)
    const unsigned short* wgt_tile = (const unsigned short*)a.WgT + (size_t)nt * NROW * KIN;
    const int brow0 = o0 >> 6;
    const int bsl0 = ((((o0 >> 4) & 3) ^ ((brow0 >> 1) & 3)) << 3);
    const char* bsT0 = (const char*)(wgt_tile + (size_t)brow0 * KIN + bsl0);
    const int ob1 = 8192 + tid * 16;
    const int brow1 = ob1 >> 6;
    const int bsl1 = ((((ob1 >> 4) & 3) ^ ((brow1 >> 1) & 3)) << 3);
    const char* bsT1 = (const char*)(wgt_tile + (size_t)brow1 * KIN + bsl1);
    const bool bv1 = (tid < 64);

    // t-invariant epilogue constants
    const int hcol = nt * 32 + wc * 16 + m16;
    const int lidx = hcol >> 6;
    float bj[4], wj[4];
#pragma unroll
    for (int j = 0; j < 4; ++j) {
        int col = nt * 128 + wc * 64 + j * 16 + m16;
        bj[j] = a.biasg[col];
        wj[j] = a.wrowg[col];
    }
    float b16r[16], w16r[16];
#pragma unroll
    for (int n = 0; n < 16; ++n) { b16r[n] = a.bias16[n]; w16r[n] = a.wrow16[n]; }

    // frag-read addresses (two buffers each)
    const unsigned short* Abase = (const unsigned short*)smem;
    const unsigned short* Bbase = (const unsigned short*)(smem + 16384);

    float creg[2][4] = {};
    ull areg[2][2];

    // pre-issue t=0 iter0 staging + x reg preloads for iters 1,2
    {
        gl_lds16(xbT, smem + o0);
        gl_lds16(bsT0, smem + 16384 + o0);
        if (bv1) gl_lds16(bsT1, smem + 16384 + ob1);
        areg[1][0] = *(const ull*)(xbT + 64);  areg[1][1] = *(const ull*)(xbT + 72);
        areg[0][0] = *(const ull*)(xbT + 128); areg[0][1] = *(const ull*)(xbT + 136);
    }
    __syncthreads();  // drain initial staging before iter0 frag reads

#pragma unroll 1
    for (int t = 0; t < T; ++t) {
        const char* xt = xbT + (size_t)t * 256;
        const char* hs = (const char*)((t & 1) ? a.h1 : a.h0) + hbyte;
        unsigned* hout32 = (unsigned*)((t & 1) ? a.h0 : a.h1);

        f32x4 acc[2][4] = {};
        f32x4 acc16[2] = {};

#pragma unroll
        for (int ki = 0; ki < 20; ++ki) {
            // Counted-vmcnt barrier (iter 0 is covered by the preceding full
            // __syncthreads). Per-iter VMEM issue order is [B-dma(+B-dma w0),
            // reload x2]; at the top of iter ki the ops that MUST be complete
            // are this iter's B tile (issued last iter) and the h/x regs
            // consumed by this iter's A-stage (issued two iters ago). vmcnt(2)
            // leaves only the newest reload pair in flight. ki==1 uses
            // vmcnt(1) (x reload pair may coalesce to one dwordx4); tail uses
            // vmcnt(0) (staging stream has ended).
            if (ki > 0) {
                if (ki == 1)
                    asm volatile("s_waitcnt vmcnt(1) lgkmcnt(0)" ::: "memory");
                else if (ki <= 17)
                    asm volatile("s_waitcnt vmcnt(2) lgkmcnt(0)" ::: "memory");
                else
                    asm volatile("s_waitcnt vmcnt(0) lgkmcnt(0)" ::: "memory");
                __builtin_amdgcn_s_barrier();
                __builtin_amdgcn_sched_barrier(0);
            }
            const int nxt = ki + 1;
            if (nxt < 20) {
                // stage A(nxt) from regs (iters 1..19; x preloaded / h pipelined)
                char* adst = smem + (nxt & 1) * 8192 + o0;
                *(ull*)adst = areg[nxt & 1][0];
                *(ull*)(adst + 8) = areg[nxt & 1][1];
                // stage B(nxt) via DMA
                char* bdst = smem + 16384 + (nxt & 1) * 9216;
                gl_lds16(bsT0 + nxt * 64, bdst + o0);
                if (bv1) gl_lds16(bsT1 + nxt * 64, bdst + ob1);
                // pin issue order: B-dma strictly before reload (vmcnt count
                // analysis above depends on it)
                __builtin_amdgcn_sched_barrier(0);
                // reload areg set for iter ki+3
                const int fut = ki + 3;
                if (fut < 20) {
                    if (fut <= 3) {
                        areg[fut & 1][0] = *(const ull*)(xt + fut * 64);
                        areg[fut & 1][1] = *(const ull*)(xt + fut * 64 + 8);
                    } else {
                        areg[fut & 1][0] = h_atomic_load(hs + fut * 64 - 256);
                        areg[fut & 1][1] = h_atomic_load(hs + fut * 64 - 248);
                    }
                }
            }
            // compute iter ki from buf ki&1
            const unsigned short* A = Abase + (ki & 1) * 4096;
            const unsigned short* Bb = Bbase + (ki & 1) * 4608;
            short8 av[2], bv[4];
#pragma unroll
            for (int i = 0; i < 2; ++i) {
                int ar = wr * 32 + i * 16 + m16;
                av[i] = *(const short8*)&A[ar * 32 + ((quad ^ ((ar >> 1) & 3)) << 3)];
            }
#pragma unroll
            for (int j = 0; j < 4; ++j) {
                int br = wc * 64 + j * 16 + m16;
                bv[j] = *(const short8*)&Bb[br * 32 + ((quad ^ ((br >> 1) & 3)) << 3)];
            }
#pragma unroll
            for (int i = 0; i < 2; ++i)
#pragma unroll
                for (int j = 0; j < 4; ++j)
                    acc[i][j] = __builtin_amdgcn_mfma_f32_16x16x32_bf16(av[i], bv[j], acc[i][j], 0, 0, 0);
            if (wc == 0) {
                int lr = 128 + m16;
                short8 wv = *(const short8*)&Bb[lr * 32 + ((quad ^ ((lr >> 1) & 3)) << 3)];
                acc16[0] = __builtin_amdgcn_mfma_f32_16x16x32_bf16(av[0], wv, acc16[0], 0, 0, 0);
                acc16[1] = __builtin_amdgcn_mfma_f32_16x16x32_bf16(av[1], wv, acc16[1], 0, 0, 0);
            }
        }
        __syncthreads();  // all frag reads done before scratch aliasing

        // logits -> LDS (wc==0 waves: wr 0..3 cover 128 rows)
        if (wc == 0) {
#pragma unroll
            for (int i = 0; i < 2; ++i)
#pragma unroll
                for (int r = 0; r < 4; ++r)
                    logitS[(wr * 32 + i * 16 + quad * 4 + r) * 17 + m16] = acc16[i][r];
        }
        __syncthreads();

        // per-row softmax-cumsum + dist: fm half on tid<128, im half on
        // tid 128..255 (independent chains)
        if (tid < 256) {
            const int row = tid & 127;
            const int m = m0 + row;
            const bool hi = tid >= 128;
            const float dt = a.tme[(size_t)m * T + t];
            if (!hi) dts[row] = dt;
            const int off = hi ? 8 : 0;
            float z[8];
#pragma unroll
            for (int n = 0; n < 8; ++n)
                z[n] = logitS[row * 17 + off + n] + b16r[off + n] + dt * w16r[off + n];
            float mx = z[0];
#pragma unroll
            for (int j = 1; j < 8; ++j) mx = fmaxf(mx, z[j]);
            float e[8], s = 0.f;
#pragma unroll
            for (int j = 0; j < 8; ++j) { e[j] = __expf(z[j] - mx); s += e[j]; }
            if (!hi) {
                float run = 0.f, fsum = 0.f;
#pragma unroll
                for (int j = 0; j < 8; ++j) { run += e[j]; float fmv = run / s; fmimS[row * 16 + j] = fmv; fsum += fmv; }
                if (nt == 0) {
                    float d = 1.0f - fsum * 0.125f;
                    a.dist_out[(size_t)t * B + m] = d;
                    if (t >= T - KW) a.tmp_ds[(size_t)(t - (T - KW)) * B + m] = d;
                }
            } else {
                float run = 0.f;
#pragma unroll
                for (int j = 7; j >= 0; --j) { run += e[j]; fmimS[row * 16 + 8 + j] = run / s; }
            }
        }
        __syncthreads();

        // gates + cell update (c in regs); h -> LDS stage
#pragma unroll
        for (int i = 0; i < 2; ++i) {
#pragma unroll
            for (int r = 0; r < 4; ++r) {
                int rl = wr * 32 + i * 16 + quad * 4 + r;
                int m = m0 + rl;
                float dt = dts[rl];
                float fmv = fmimS[rl * 16 + lidx];
                float imv = fmimS[rl * 16 + 8 + lidx];
                float fg = fsigmoid_(acc[i][0][r] + bj[0] + dt * wj[0]);
                float ig = fsigmoid_(acc[i][1][r] + bj[1] + dt * wj[1]);
                float og = fsigmoid_(acc[i][2][r] + bj[2] + dt * wj[2]);
                float ci = ftanh_(acc[i][3][r] + bj[3] + dt * wj[3]);
                float ov = fmv * imv;
                float cl = creg[i][r];
                float cn = ov * (fg * cl + ig * ci) + (fmv - ov) * cl + (imv - ov) * ci;
                float hn = og * ftanh_(cn);
                creg[i][r] = cn;
                __hip_bfloat16 hb = __float2bfloat16(hn);
                hstageS[rl * 32 + (wc * 16 + m16)] = *(unsigned short*)&hb;
                if (t >= T - KW) a.tmp_h[((size_t)(t - (T - KW)) * B + m) * H + hcol] = hb;
            }
        }
        __syncthreads();

        // pack h pairs -> agent-scope atomic dword stores
        {
            const unsigned* hs32 = (const unsigned*)hstageS;
#pragma unroll
            for (int wds = 0; wds < 4; ++wds) {
                int wi = wds * 512 + tid;
                int row = wi >> 4, cp = wi & 15;
                unsigned v = hs32[row * 16 + cp];
                __hip_atomic_store(hout32 + (size_t)(m0 + row) * (H / 2) + nt * 16 + cp, v,
                                   __ATOMIC_RELAXED, __HIP_MEMORY_SCOPE_AGENT);
            }
        }

        __syncthreads();  // pack reads done + stores drained (vmcnt0)
        if (t != T - 1) {
            // pre-issue next step's iter0 staging + x preloads (fly during spin)
            const char* xn = xbT + (size_t)(t + 1) * 256;
            gl_lds16(xn, smem + o0);
            gl_lds16(bsT0, smem + 16384 + o0);
            if (bv1) gl_lds16(bsT1, smem + 16384 + ob1);
            areg[1][0] = *(const ull*)(xn + 64);  areg[1][1] = *(const ull*)(xn + 72);
            areg[0][0] = *(const ull*)(xn + 128); areg[0][1] = *(const ull*)(xn + 136);
            // per-mt-group barrier: the 16 nt blocks of this mt are a closed
            // set for h (rows m0..m0+127 only). Monotone counter, target
            // 16*(t+1); groups drift independently.
            if (tid == 0) {
                unsigned* ctr = a.bar + (mt << 6);
                __hip_atomic_fetch_add(ctr, 1u, __ATOMIC_RELAXED, __HIP_MEMORY_SCOPE_AGENT);
                const unsigned tgt = 16u * (unsigned)(t + 1);
                for (int it = 0; it < (1 << 22); ++it) {
                    if (__hip_atomic_load(ctr, __ATOMIC_RELAXED, __HIP_MEMORY_SCOPE_AGENT) >= tgt) break;
                    __builtin_amdgcn_s_sleep(2);
                }
            }
            __syncthreads();  // also drains pre-issued staging (vmcnt0)
        }
    }
}

// ---------- post (unchanged) ----------
__global__ __launch_bounds__(128) void post_local(
    const __hip_bfloat16* __restrict__ tmp_h, const float* __restrict__ tmp_dis,
    float* __restrict__ mean_h, __hip_bfloat16* __restrict__ Ahk)
{
    const int b = blockIdx.x;
    const int tid = threadIdx.x;
    __shared__ float ld[KW];
    if (tid == 0) {
        float cd[KW];
        float run = 0.f;
        for (int k = 0; k < KW; ++k) { run += tmp_dis[(size_t)k * B + b]; cd[k] = run; }
        float mx = cd[0];
        for (int k = 1; k < KW; ++k) mx = fmaxf(mx, cd[k]);
        float s = 0.f;
        for (int k = 0; k < KW; ++k) { cd[k] = expf(cd[k] - mx); s += cd[k]; }
        for (int k = 0; k < KW; ++k) ld[k] = cd[k] / s;
    }
    __syncthreads();
    float ldr[KW];
#pragma unroll
    for (int k = 0; k < KW; ++k) ldr[k] = ld[k];
    for (int h = tid; h < H; h += 128) {
        float s = 0.f;
#pragma unroll
        for (int k = 0; k < KW; ++k) {
            float v = __bfloat162float(tmp_h[((size_t)k * B + b) * H + h]) * ldr[k];
            s += v;
            Ahk[(size_t)b * RC + h * KW + k] = __float2bfloat16(v);
        }
        mean_h[(size_t)b * H + h] = s * (1.0f / KW);
    }
}

__global__ void theme1_k(const float* __restrict__ mean_h, const float* __restrict__ Ws,
                         const float* __restrict__ bs, float* __restrict__ t1)
{
    int idx = blockIdx.x * blockDim.x + threadIdx.x;
    if (idx >= B * HS) return;
    int b = idx / HS, j = idx % HS;
    float s = bs[j];
    const float* mh = mean_h + (size_t)b * H;
    for (int h = 0; h < H; ++h) s += mh[h] * Ws[(size_t)h * HS + j];
    t1[idx] = fmaxf(s, 0.f);
}

__global__ void theme2_k(const float* __restrict__ t1, const float* __restrict__ Wrs,
                         const float* __restrict__ brs, float* __restrict__ theme)
{
    int idx = blockIdx.x * blockDim.x + threadIdx.x;
    if (idx >= B * H) return;
    int b = idx / H, o = idx % H;
    float s = brs[o];
    const float* tv = t1 + (size_t)b * HS;
    for (int j = 0; j < HS; ++j) s += tv[j] * Wrs[(size_t)j * H + o];
    theme[idx] = 1.0f / (1.0f + expf(-s));
}

__global__ __launch_bounds__(256) void conv_split(
    const __hip_bfloat16* __restrict__ Ahk, const __hip_bfloat16* __restrict__ CWb,
    float* __restrict__ Pbuf)
{
    __shared__ __align__(16) unsigned short As2[128 * 64];
    __shared__ __align__(16) unsigned short Bs2[128 * 64];
    const int tid = threadIdx.x;
    const int wave = tid >> 6;
    const int wr = wave >> 1, wc = wave & 1;
    const int quad = (tid & 63) >> 4, m16 = tid & 15;
    const int n0 = blockIdx.x * 128, m0 = blockIdx.y * 128;
    const int ksb = blockIdx.z * (RC / KS);

    f32x4 acc[4][4] = {};
    for (int k0 = 0; k0 < RC / KS; k0 += 64) {
#pragma unroll
        for (int p = 0; p < 4; ++p) {
            int o = p * 4096 + tid * 16;
            int row = o >> 7, slot = (o >> 4) & 7;
            int kg = ksb + k0 + (slot ^ (row & 7)) * 8;
            gl_lds16((const unsigned short*)Ahk + (size_t)(m0 + row) * RC + kg, (char*)As2 + o);
            gl_lds16((const unsigned short*)CWb + (size_t)(n0 + row) * RC + kg, (char*)Bs2 + o);
        }
        __syncthreads();
#pragma unroll
        for (int c2 = 0; c2 < 2; ++c2) {
            const int k8 = c2 * 4 + quad;
            short8 av[4], bv[4];
#pragma unroll
            for (int i = 0; i < 4; ++i) {
                int arow = wr * 64 + i * 16 + m16;
                av[i] = *(const short8*)&As2[arow * 64 + (k8 ^ (arow & 7)) * 8];
            }
#pragma unroll
            for (int j = 0; j < 4; ++j) {
                int brow = wc * 64 + j * 16 + m16;
                bv[j] = *(const short8*)&Bs2[brow * 64 + (k8 ^ (brow & 7)) * 8];
            }
#pragma unroll
            for (int i = 0; i < 4; ++i)
#pragma unroll
                for (int j = 0; j < 4; ++j)
                    acc[i][j] = __builtin_amdgcn_mfma_f32_16x16x32_bf16(av[i], bv[j], acc[i][j], 0, 0, 0);
        }
        __syncthreads();
    }
    float* P = Pbuf + (size_t)blockIdx.z * B * H;
#pragma unroll
    for (int j = 0; j < 4; ++j) {
        const int col = n0 + wc * 64 + j * 16 + m16;
#pragma unroll
        for (int i = 0; i < 4; ++i) {
            const int rb = m0 + wr * 64 + i * 16 + quad * 4;
#pragma unroll
            for (int r = 0; r < 4; ++r)
                P[(size_t)(rb + r) * H + col] = acc[i][j][r];
        }
    }
}

__global__ void conv_reduce(const float* __restrict__ Pbuf, const float* __restrict__ conv_b,
                            const float* __restrict__ theme, float* __restrict__ out0)
{
    int i = blockIdx.x * blockDim.x + threadIdx.x;
    if (i >= B * H) return;
    float s = conv_b[i & (H - 1)];
#pragma unroll
    for (int ks = 0; ks < KS; ++ks) s += Pbuf[(size_t)ks * B * H + i];
    out0[i] = theme[i] * s;
}

} // namespace

extern "C" void kernel_launch(void* const* d_in, const int* in_sizes, int n_in,
                              void* d_out, int out_size, void* d_ws, size_t ws_size,
                              hipStream_t stream)
{
    (void)in_sizes; (void)n_in; (void)out_size; (void)ws_size;
    const float* x      = (const float*)d_in[0];
    const float* tme    = (const float*)d_in[1];
    const float* Wk     = (const float*)d_in[2];
    const float* bk     = (const float*)d_in[3];
    const float* Wr     = (const float*)d_in[4];
    const float* br     = (const float*)d_in[5];
    const float* Ws     = (const float*)d_in[6];
    const float* bs     = (const float*)d_in[7];
    const float* Wrs    = (const float*)d_in[8];
    const float* brs    = (const float*)d_in[9];
    const float* conv_w = (const float*)d_in[10];
    const float* conv_b = (const float*)d_in[11];

    float* out0 = (float*)d_out;
    float* dist_out = out0 + (size_t)B * H;

    // workspace carve (~162 MB)
    char* w = (char*)d_ws;
    __hip_bfloat16* WgT  = (__hip_bfloat16*)w; w += (size_t)16 * NROW * KIN * 2;
    __hip_bfloat16* xb   = (__hip_bfloat16*)w; w += (size_t)B * T * F * 2;
    __hip_bfloat16* CWb  = (__hip_bfloat16*)w; w += (size_t)H * RC * 2;
    __hip_bfloat16* Ahk  = (__hip_bfloat16*)w; w += (size_t)B * RC * 2;
    __hip_bfloat16* hb0  = (__hip_bfloat16*)w; w += (size_t)B * H * 2;
    __hip_bfloat16* hb1  = (__hip_bfloat16*)w; w += (size_t)B * H * 2;
    __hip_bfloat16* tmp_h = (__hip_bfloat16*)w; w += (size_t)KW * B * H * 2;
    float* biasg  = (float*)w; w += (size_t)NG * 4;
    float* wrowg  = (float*)w; w += (size_t)NG * 4;
    float* bias16 = (float*)w; w += 64;
    float* wrow16 = (float*)w; w += 64;
    float* tmp_ds = (float*)w; w += (size_t)KW * B * 4;
    float* mean_h = (float*)w; w += (size_t)B * H * 4;
    float* t1     = (float*)w; w += (size_t)B * HS * 4;
    float* theme  = (float*)w; w += (size_t)B * H * 4;
    float* Pbuf   = (float*)w; w += (size_t)KS * B * H * 4;
    unsigned* bar = (unsigned*)w; w += 4096;

    hipMemsetAsync(hb0, 0, (size_t)B * H * sizeof(__hip_bfloat16), stream);
    hipMemsetAsync(bar, 0, 4096, stream);

    prep_wgt<<<dim3(NG / 64, KIN / 64), 256, 0, stream>>>(Wk, Wr, WgT);
    prep_w16rep<<<(16 * 16 * KIN + 255) / 256, 256, 0, stream>>>(Wk, Wr, WgT);
    prep_small<<<1, 256, 0, stream>>>(Wk, bk, Wr, br, biasg, wrowg, bias16, wrow16);
    convert_x<<<((B * T * F / 4) + 255) / 256, 256, 0, stream>>>(x, xb);
    prep_convw<<<((H * RC / 4) + 255) / 256, 256, 0, stream>>>(conv_w, CWb);

    {
        StepArgs sa;
        sa.xb = xb; sa.h0 = hb0; sa.h1 = hb1; sa.WgT = WgT;
        sa.biasg = biasg; sa.wrowg = wrowg; sa.bias16 = bias16; sa.wrow16 = wrow16;
        sa.tme = tme; sa.tmp_h = tmp_h; sa.tmp_ds = tmp_ds; sa.dist_out = dist_out;
        sa.bar = bar;
        persistent_step<<<256, 512, 0, stream>>>(sa);
    }

    post_local<<<B, 128, 0, stream>>>(tmp_h, tmp_ds, mean_h, Ahk);
    theme1_k<<<(B * HS + 255) / 256, 256, 0, stream>>>(mean_h, Ws, bs, t1);
    theme2_k<<<(B * H + 255) / 256, 256, 0, stream>>>(t1, Wrs, brs, theme);
    conv_split<<<dim3(H / 128, B / 128, KS), 256, 0, stream>>>(Ahk, CWb, Pbuf);
    conv_reduce<<<(B * H + 255) / 256, 256, 0, stream>>>(Pbuf, conv_b, theme, out0);
}

// Round 2
// 1770.953 us; speedup vs baseline: 1.3396x; 1.1851x over previous
//
#include <hip/hip_runtime.h>
#include <hip/hip_bf16.h>
#include <cstddef>
#include <cstdint>

namespace {

constexpr int B = 2048, T = 128, F = 128, H = 512, L = 8, KW = 10;
constexpr int GATES = 2064;
constexpr int NG = 2048;    // gate columns (permuted)
constexpr int KIN = 640;    // F + H
constexpr int HS = 85;      // H // 6
constexpr int RC = H * KW;  // 5120
constexpr int KS = 8;       // conv split-K slices
constexpr int NROW = 144;   // Bs rows per tile: 128 gates + 16 logit cols

// LDS layout for persistent_step (total 155136 B, 1 block/CU):
constexpr int ABUF = 0;          // A double buffer 2x8192
constexpr int BRES = 16384;      // resident B slices 0..11 (12 x 9216)
constexpr int BROT = 126976;     // rotating B ring, 3 x 9216 (slices 12..19)
constexpr int DTSO = 154624;     // dts 512 B (dedicated, never aliased)
constexpr int SMEM_SZ = 155136;

typedef __attribute__((ext_vector_type(8))) short short8;
typedef __attribute__((ext_vector_type(4))) float f32x4;
typedef unsigned long long ull;

__device__ __forceinline__ float fsigmoid_(float x) {
    return __builtin_amdgcn_rcpf(1.0f + __expf(-x));
}
__device__ __forceinline__ float ftanh_(float x) {
    return 1.0f - 2.0f * __builtin_amdgcn_rcpf(1.0f + __expf(2.0f * x));
}

__device__ __forceinline__ void gl_lds16(const void* g, void* l) {
    __builtin_amdgcn_global_load_lds(
        (const __attribute__((address_space(1))) unsigned int*)g,
        (__attribute__((address_space(3))) unsigned int*)l,
        16, 0, 0);
}

__device__ __forceinline__ ull h_atomic_load(const void* p) {
    return __hip_atomic_load((const ull*)p, __ATOMIC_RELAXED, __HIP_MEMORY_SCOPE_AGENT);
}

// ---------- prep ----------
__global__ __launch_bounds__(256) void prep_wgt(
    const float* __restrict__ Wk, const float* __restrict__ Wr,
    __hip_bfloat16* __restrict__ WgT)
{
    __shared__ float tile[64 * 65];
    const int tid = threadIdx.x;
    const int c0 = blockIdx.x * 64, k0 = blockIdx.y * 64;
#pragma unroll
    for (int rep = 0; rep < 16; ++rep) {
        int e = rep * 256 + tid;
        int kl = e >> 6, cl = e & 63;
        int col = c0 + cl;
        int nt = col >> 7, cc = col & 127;
        int n = 16 + ((cc >> 4) & 3) * 512 + nt * 32 + ((cc >> 6) & 1) * 16 + (cc & 15);
        int k = k0 + kl;
        tile[kl * 65 + cl] = (k < F) ? Wk[(size_t)k * GATES + n] : Wr[(size_t)(k - F) * GATES + n];
    }
    __syncthreads();
    const int cl = tid >> 2, q = tid & 3;
    unsigned short buf[16];
#pragma unroll
    for (int i = 0; i < 16; ++i) {
        float f = tile[(q * 16 + i) * 65 + cl];
        __hip_bfloat16 bv = __float2bfloat16(f);
        buf[i] = *(unsigned short*)&bv;
    }
    int col = c0 + cl;
    int nt = col >> 7, rin = col & 127;
    unsigned short* dst = (unsigned short*)WgT + (size_t)nt * NROW * KIN + (size_t)rin * KIN + k0 + q * 16;
    *(short8*)dst = *(short8*)&buf[0];
    *(short8*)(dst + 8) = *(short8*)&buf[8];
}

__global__ void prep_w16rep(const float* __restrict__ Wk, const float* __restrict__ Wr,
                            __hip_bfloat16* __restrict__ WgT)
{
    int idx = blockIdx.x * blockDim.x + threadIdx.x;
    if (idx >= 16 * 16 * KIN) return;
    int nt = idx / (16 * KIN);
    int rem = idx % (16 * KIN);
    int n = rem / KIN, k = rem % KIN;
    float v = (k < F) ? Wk[(size_t)k * GATES + n] : Wr[(size_t)(k - F) * GATES + n];
    WgT[(size_t)nt * NROW * KIN + (size_t)(128 + n) * KIN + k] = __float2bfloat16(v);
}

__global__ void prep_small(const float* __restrict__ Wk, const float* __restrict__ bk,
                           const float* __restrict__ Wr, const float* __restrict__ br,
                           float* __restrict__ biasg, float* __restrict__ wrowg,
                           float* __restrict__ bias16, float* __restrict__ wrow16)
{
    const int total = 2 * NG + 32;
    for (int idx = threadIdx.x; idx < total; idx += 256) {
        if (idx < NG) {
            int col = idx;
            int nt = col >> 7, cc = col & 127;
            int n = 16 + ((cc >> 4) & 3) * 512 + nt * 32 + ((cc >> 6) & 1) * 16 + (cc & 15);
            biasg[col] = bk[n] + br[n];
        } else if (idx < 2 * NG) {
            int col = idx - NG;
            int nt = col >> 7, cc = col & 127;
            int n = 16 + ((cc >> 4) & 3) * 512 + nt * 32 + ((cc >> 6) & 1) * 16 + (cc & 15);
            wrowg[col] = Wk[(size_t)F * GATES + n] + Wr[(size_t)H * GATES + n];
        } else if (idx < 2 * NG + 16) {
            int n = idx - 2 * NG;
            bias16[n] = bk[n] + br[n];
        } else {
            int n = idx - 2 * NG - 16;
            wrow16[n] = Wk[(size_t)F * GATES + n] + Wr[(size_t)H * GATES + n];
        }
    }
}

__global__ void convert_x(const float* __restrict__ x, __hip_bfloat16* __restrict__ xb) {
    int i = blockIdx.x * blockDim.x + threadIdx.x;
    size_t o = (size_t)i * 4;
    if (o >= (size_t)B * T * F) return;
    float4 v = *(const float4*)(x + o);
    xb[o + 0] = __float2bfloat16(v.x);
    xb[o + 1] = __float2bfloat16(v.y);
    xb[o + 2] = __float2bfloat16(v.z);
    xb[o + 3] = __float2bfloat16(v.w);
}

__global__ void prep_convw(const float* __restrict__ conv_w, __hip_bfloat16* __restrict__ CWb) {
    int i = blockIdx.x * blockDim.x + threadIdx.x;
    if (i >= H * RC / 4) return;
    size_t o = (size_t)i * 4;
    float4 v = *(const float4*)(conv_w + o);
    CWb[o + 0] = __float2bfloat16(v.x);
    CWb[o + 1] = __float2bfloat16(v.y);
    CWb[o + 2] = __float2bfloat16(v.z);
    CWb[o + 3] = __float2bfloat16(v.w);
}

// tme [B,T] -> tmeT [T,B] (coalesced epilogue loads in persistent_step)
__global__ __launch_bounds__(256) void prep_tmet(const float* __restrict__ tin,
                                                 float* __restrict__ tout)
{
    __shared__ float tl[32][33];
    const int bb = blockIdx.x * 32, tt = blockIdx.y * 32;
    const int tx = threadIdx.x & 31, ty = threadIdx.x >> 5;  // ty 0..7
#pragma unroll
    for (int r = 0; r < 32; r += 8)
        tl[ty + r][tx] = tin[(size_t)(bb + ty + r) * T + tt + tx];
    __syncthreads();
#pragma unroll
    for (int r = 0; r < 32; r += 8)
        tout[(size_t)(tt + ty + r) * B + bb + tx] = tl[tx][ty + r];
}

// ---------- persistent fused step ----------
struct StepArgs {
    const __hip_bfloat16* xb;
    __hip_bfloat16* h0;
    __hip_bfloat16* h1;
    const __hip_bfloat16* WgT;
    const float* biasg;
    const float* wrowg;
    const float* bias16;
    const float* wrow16;
    const float* tmeT;   // [T, B]
    __hip_bfloat16* tmp_h;
    float* tmp_ds;
    float* dist_out;
    unsigned* bar;  // per-mt-group counters, 256 B apart
};

// 256 blocks (16 mt x 16 nt, XCD-swizzled), 512 threads. M-tile 128, N-tile
// 128(+16 logit rows), BK 32, fully unrolled 20-iter k-loop.
// R10: B (t-invariant) slices 0..11 RESIDENT in LDS (staged once); slices
// 12..19 rotate through a 3-buffer ring with 2-iter prefetch distance and
// exact counted vmcnt. 12/20 iters have no VMEM wait at all, so the 3-iter
// h prefetch pipeline is never drained early. tme pre-transposed + loaded
// coalesced at step top into dedicated dts LDS. Softmax divides -> rcp*mul.
__global__ __launch_bounds__(512, 2) void persistent_step(StepArgs a)
{
    __shared__ __align__(16) char smem[SMEM_SZ];
    // epilogue aliases (A bufs + rotating-B ring are dead by epilogue;
    // resident B region 16384..126976 is NEVER aliased):
    float* logitS = (float*)smem;                               // 128*17*4 = 8704 @0
    float* fmimS = (float*)(smem + BROT);                       // 8192 @126976
    unsigned short* hstageS = (unsigned short*)(smem + 135168); // 8192
    float* dts = (float*)(smem + DTSO);                         // 512 (dedicated)

    const int tid = threadIdx.x;
    const int wave = tid >> 6;
    const int wr = wave >> 1, wc = wave & 1;   // wr 0..3, wc 0..1
    const int quad = (tid & 63) >> 4, m16 = tid & 15;
    const int l = blockIdx.x;
    const int nt = ((l & 7) << 1) | ((l >> 3) & 1);  // same-nt -> same XCD
    const int mt = l >> 4;
    const int m0 = mt * 128;

    // ---- per-thread staging geometry (A tile 128x32 bf16 = 8 KB; 16 B/thread)
    const int o0 = tid * 16;
    const int arow = o0 >> 6;                       // 64 B per row
    const int asl = ((((o0 >> 4) & 3) ^ ((arow >> 1) & 3)) << 3);  // k-elt offset
    const char* xbT = (const char*)a.xb + (size_t)(m0 + arow) * (T * F * 2) + asl * 2;
    const size_t hbyte = (size_t)(m0 + arow) * (H * 2) + asl * 2;
    // Bs: 144x32 bf16 = 9216 B; p0 = tid*16 (all), p1 = 8192 + tid*16 (tid<64)
    const unsigned short* wgt_tile = (const unsigned short*)a.WgT + (size_t)nt * NROW * KIN;
    const int brow0 = o0 >> 6;
    const int bsl0 = ((((o0 >> 4) & 3) ^ ((brow0 >> 1) & 3)) << 3);
    const char* bsT0 = (const char*)(wgt_tile + (size_t)brow0 * KIN + bsl0);
    const int ob1 = 8192 + tid * 16;
    const int brow1 = ob1 >> 6;
    const int bsl1 = ((((ob1 >> 4) & 3) ^ ((brow1 >> 1) & 3)) << 3);
    const char* bsT1 = (const char*)(wgt_tile + (size_t)brow1 * KIN + bsl1);
    const bool bv1 = (tid < 64);   // wave-uniform

    auto stageB = [&](int s, int bufbyte) {
        gl_lds16(bsT0 + s * 64, smem + bufbyte + o0);
        if (bv1) gl_lds16(bsT1 + s * 64, smem + bufbyte + ob1);
    };

    // t-invariant epilogue constants
    const int hcol = nt * 32 + wc * 16 + m16;
    const int lidx = hcol >> 6;
    float bj[4], wj[4];
#pragma unroll
    for (int j = 0; j < 4; ++j) {
        int col = nt * 128 + wc * 64 + j * 16 + m16;
        bj[j] = a.biasg[col];
        wj[j] = a.wrowg[col];
    }
    float b16r[16], w16r[16];
#pragma unroll
    for (int n = 0; n < 16; ++n) { b16r[n] = a.bias16[n]; w16r[n] = a.wrow16[n]; }

    const unsigned short* Abase = (const unsigned short*)smem;

    float creg[2][4] = {};
    ull areg[2][2];

    // ---- prologue: stage resident B slices 0..11 once; pre-issue t=0 iter0
    {
#pragma unroll
        for (int s = 0; s < 12; ++s) stageB(s, BRES + s * 9216);
        gl_lds16(xbT, smem + o0);               // A(0)
        stageB(12, BROT + 0 * 9216);            // rot ring entries for t=0
        stageB(13, BROT + 1 * 9216);
        areg[1][0] = h_atomic_load(xbT + 64);  areg[1][1] = h_atomic_load(xbT + 72);
        areg[0][0] = h_atomic_load(xbT + 128); areg[0][1] = h_atomic_load(xbT + 136);
    }
    __syncthreads();  // drain all prologue staging before iter0 frag reads

#pragma unroll 1
    for (int t = 0; t < T; ++t) {
        const char* xt = xbT + (size_t)t * 256;
        const char* hs = (const char*)((t & 1) ? a.h1 : a.h0) + hbyte;
        unsigned* hout32 = (unsigned*)((t & 1) ? a.h0 : a.h1);

        // step-top: coalesced dt load -> dedicated dts LDS (off epilogue path)
        if (tid < 128) dts[tid] = a.tmeT[(size_t)t * B + m0 + tid];

        f32x4 acc[2][4] = {};
        f32x4 acc16[2] = {};

#pragma unroll
        for (int ki = 0; ki < 20; ++ki) {
            // Barrier + wait policy:
            //  ki 1..13 : B resident (0..11) or pre-staged+drained (12,13):
            //             lgkmcnt(0) only -- h prefetches stay in flight.
            //  ki 14..17: B(ki) DMA'd at iter ki-2. Ops issued after it:
            //             h(ki+1) x2 + B(ki+1) x c + h(ki+2) x2 -> vmcnt(4+c).
            //  ki 18    : after B(18): h(19) x2 + B(19) x c -> vmcnt(2+c).
            //  ki 19    : nothing issued after B(19) -> vmcnt(0).
            if (ki > 0) {
                if (ki <= 13) {
                    asm volatile("s_waitcnt lgkmcnt(0)" ::: "memory");
                } else if (ki <= 17) {
                    if (bv1) asm volatile("s_waitcnt vmcnt(6) lgkmcnt(0)" ::: "memory");
                    else     asm volatile("s_waitcnt vmcnt(5) lgkmcnt(0)" ::: "memory");
                } else if (ki == 18) {
                    if (bv1) asm volatile("s_waitcnt vmcnt(4) lgkmcnt(0)" ::: "memory");
                    else     asm volatile("s_waitcnt vmcnt(3) lgkmcnt(0)" ::: "memory");
                } else {
                    asm volatile("s_waitcnt vmcnt(0) lgkmcnt(0)" ::: "memory");
                }
                __builtin_amdgcn_s_barrier();
                __builtin_amdgcn_sched_barrier(0);
            }
            const int nxt = ki + 1;
            if (nxt < 20) {
                // stage A(nxt) from regs
                char* adst = smem + (nxt & 1) * 8192 + o0;
                *(ull*)adst = areg[nxt & 1][0];
                *(ull*)(adst + 8) = areg[nxt & 1][1];
            }
            // rotating-B DMA: slice s = ki+2 (14..19) -> ring buf (s-12)%3.
            // Write-after-read safe: ring slot last held B(s-3), fully read
            // at iter s-3, guaranteed done by barrier at top of iter s-2.
            if (ki >= 12 && ki <= 17) {
                const int s = ki + 2;
                stageB(s, BROT + ((s - 12) % 3) * 9216);
            }
            __builtin_amdgcn_sched_barrier(0);  // pin DMA before reg loads
            // reload areg set for iter ki+3
            const int fut = ki + 3;
            if (fut < 20) {
                if (fut <= 3) {
                    areg[fut & 1][0] = h_atomic_load(xt + fut * 64);
                    areg[fut & 1][1] = h_atomic_load(xt + fut * 64 + 8);
                } else {
                    areg[fut & 1][0] = h_atomic_load(hs + fut * 64 - 256);
                    areg[fut & 1][1] = h_atomic_load(hs + fut * 64 - 248);
                }
            }
            __builtin_amdgcn_sched_barrier(0);  // pin reg loads before frag reads
            // compute iter ki: A from dbuf ki&1, B from resident or ring
            const unsigned short* A = Abase + (ki & 1) * 4096;
            const unsigned short* Bb = (const unsigned short*)
                (smem + (ki < 12 ? BRES + ki * 9216 : BROT + ((ki - 12) % 3) * 9216));
            short8 av[2], bv[4];
#pragma unroll
            for (int i = 0; i < 2; ++i) {
                int ar = wr * 32 + i * 16 + m16;
                av[i] = *(const short8*)&A[ar * 32 + ((quad ^ ((ar >> 1) & 3)) << 3)];
            }
#pragma unroll
            for (int j = 0; j < 4; ++j) {
                int br = wc * 64 + j * 16 + m16;
                bv[j] = *(const short8*)&Bb[br * 32 + ((quad ^ ((br >> 1) & 3)) << 3)];
            }
#pragma unroll
            for (int i = 0; i < 2; ++i)
#pragma unroll
                for (int j = 0; j < 4; ++j)
                    acc[i][j] = __builtin_amdgcn_mfma_f32_16x16x32_bf16(av[i], bv[j], acc[i][j], 0, 0, 0);
            if (wc == 0) {
                int lr = 128 + m16;
                short8 wv = *(const short8*)&Bb[lr * 32 + ((quad ^ ((lr >> 1) & 3)) << 3)];
                acc16[0] = __builtin_amdgcn_mfma_f32_16x16x32_bf16(av[0], wv, acc16[0], 0, 0, 0);
                acc16[1] = __builtin_amdgcn_mfma_f32_16x16x32_bf16(av[1], wv, acc16[1], 0, 0, 0);
            }
        }
        __syncthreads();  // all frag reads done before scratch aliasing

        // logits -> LDS (wc==0 waves: wr 0..3 cover 128 rows)
        if (wc == 0) {
#pragma unroll
            for (int i = 0; i < 2; ++i)
#pragma unroll
                for (int r = 0; r < 4; ++r)
                    logitS[(wr * 32 + i * 16 + quad * 4 + r) * 17 + m16] = acc16[i][r];
        }
        __syncthreads();

        // per-row softmax-cumsum + dist: fm half on tid<128, im half on
        // tid 128..255 (independent chains); dt from LDS (preloaded)
        if (tid < 256) {
            const int row = tid & 127;
            const int m = m0 + row;
            const bool hi = tid >= 128;
            const float dt = dts[row];
            const int off = hi ? 8 : 0;
            float z[8];
#pragma unroll
            for (int n = 0; n < 8; ++n)
                z[n] = logitS[row * 17 + off + n] + b16r[off + n] + dt * w16r[off + n];
            float mx = z[0];
#pragma unroll
            for (int j = 1; j < 8; ++j) mx = fmaxf(mx, z[j]);
            float e[8], s = 0.f;
#pragma unroll
            for (int j = 0; j < 8; ++j) { e[j] = __expf(z[j] - mx); s += e[j]; }
            const float inv = __builtin_amdgcn_rcpf(s);
            if (!hi) {
                float run = 0.f, fsum = 0.f;
#pragma unroll
                for (int j = 0; j < 8; ++j) { run += e[j]; float fmv = run * inv; fmimS[row * 16 + j] = fmv; fsum += fmv; }
                if (nt == 0) {
                    float d = 1.0f - fsum * 0.125f;
                    a.dist_out[(size_t)t * B + m] = d;
                    if (t >= T - KW) a.tmp_ds[(size_t)(t - (T - KW)) * B + m] = d;
                }
            } else {
                float run = 0.f;
#pragma unroll
                for (int j = 7; j >= 0; --j) { run += e[j]; fmimS[row * 16 + 8 + j] = run * inv; }
            }
        }
        __syncthreads();

        // gates + cell update (c in regs); h -> LDS stage
#pragma unroll
        for (int i = 0; i < 2; ++i) {
#pragma unroll
            for (int r = 0; r < 4; ++r) {
                int rl = wr * 32 + i * 16 + quad * 4 + r;
                int m = m0 + rl;
                float dt = dts[rl];
                float fmv = fmimS[rl * 16 + lidx];
                float imv = fmimS[rl * 16 + 8 + lidx];
                float fg = fsigmoid_(acc[i][0][r] + bj[0] + dt * wj[0]);
                float ig = fsigmoid_(acc[i][1][r] + bj[1] + dt * wj[1]);
                float og = fsigmoid_(acc[i][2][r] + bj[2] + dt * wj[2]);
                float ci = ftanh_(acc[i][3][r] + bj[3] + dt * wj[3]);
                float ov = fmv * imv;
                float cl = creg[i][r];
                float cn = ov * (fg * cl + ig * ci) + (fmv - ov) * cl + (imv - ov) * ci;
                float hn = og * ftanh_(cn);
                creg[i][r] = cn;
                __hip_bfloat16 hb = __float2bfloat16(hn);
                hstageS[rl * 32 + (wc * 16 + m16)] = *(unsigned short*)&hb;
                if (t >= T - KW) a.tmp_h[((size_t)(t - (T - KW)) * B + m) * H + hcol] = hb;
            }
        }
        __syncthreads();

        // pack h pairs -> agent-scope atomic dword stores
        {
            const unsigned* hs32 = (const unsigned*)hstageS;
#pragma unroll
            for (int wds = 0; wds < 4; ++wds) {
                int wi = wds * 512 + tid;
                int row = wi >> 4, cp = wi & 15;
                unsigned v = hs32[row * 16 + cp];
                __hip_atomic_store(hout32 + (size_t)(m0 + row) * (H / 2) + nt * 16 + cp, v,
                                   __ATOMIC_RELAXED, __HIP_MEMORY_SCOPE_AGENT);
            }
        }

        __syncthreads();  // pack reads done + h stores drained (vmcnt0)
        if (t != T - 1) {
            // pre-issue next step's iter0 A + rot-ring B(12),B(13) + x preloads
            // (all fly during the spin; drained by the post-spin barrier)
            const char* xn = xbT + (size_t)(t + 1) * 256;
            gl_lds16(xn, smem + o0);
            stageB(12, BROT + 0 * 9216);
            stageB(13, BROT + 1 * 9216);
            areg[1][0] = h_atomic_load(xn + 64);  areg[1][1] = h_atomic_load(xn + 72);
            areg[0][0] = h_atomic_load(xn + 128); areg[0][1] = h_atomic_load(xn + 136);
            // per-mt-group barrier (16 nt blocks = closed h-communication set)
            if (tid == 0) {
                unsigned* ctr = a.bar + (mt << 6);
                __hip_atomic_fetch_add(ctr, 1u, __ATOMIC_RELAXED, __HIP_MEMORY_SCOPE_AGENT);
                const unsigned tgt = 16u * (unsigned)(t + 1);
                for (int it = 0; it < (1 << 22); ++it) {
                    if (__hip_atomic_load(ctr, __ATOMIC_RELAXED, __HIP_MEMORY_SCOPE_AGENT) >= tgt) break;
                    __builtin_amdgcn_s_sleep(2);
                }
            }
            __syncthreads();  // releases block + drains pre-issued staging
        }
    }
}

// ---------- post (unchanged) ----------
__global__ __launch_bounds__(128) void post_local(
    const __hip_bfloat16* __restrict__ tmp_h, const float* __restrict__ tmp_dis,
    float* __restrict__ mean_h, __hip_bfloat16* __restrict__ Ahk)
{
    const int b = blockIdx.x;
    const int tid = threadIdx.x;
    __shared__ float ld[KW];
    if (tid == 0) {
        float cd[KW];
        float run = 0.f;
        for (int k = 0; k < KW; ++k) { run += tmp_dis[(size_t)k * B + b]; cd[k] = run; }
        float mx = cd[0];
        for (int k = 1; k < KW; ++k) mx = fmaxf(mx, cd[k]);
        float s = 0.f;
        for (int k = 0; k < KW; ++k) { cd[k] = expf(cd[k] - mx); s += cd[k]; }
        for (int k = 0; k < KW; ++k) ld[k] = cd[k] / s;
    }
    __syncthreads();
    float ldr[KW];
#pragma unroll
    for (int k = 0; k < KW; ++k) ldr[k] = ld[k];
    for (int h = tid; h < H; h += 128) {
        float s = 0.f;
#pragma unroll
        for (int k = 0; k < KW; ++k) {
            float v = __bfloat162float(tmp_h[((size_t)k * B + b) * H + h]) * ldr[k];
            s += v;
            Ahk[(size_t)b * RC + h * KW + k] = __float2bfloat16(v);
        }
        mean_h[(size_t)b * H + h] = s * (1.0f / KW);
    }
}

__global__ void theme1_k(const float* __restrict__ mean_h, const float* __restrict__ Ws,
                         const float* __restrict__ bs, float* __restrict__ t1)
{
    int idx = blockIdx.x * blockDim.x + threadIdx.x;
    if (idx >= B * HS) return;
    int b = idx / HS, j = idx % HS;
    float s = bs[j];
    const float* mh = mean_h + (size_t)b * H;
    for (int h = 0; h < H; ++h) s += mh[h] * Ws[(size_t)h * HS + j];
    t1[idx] = fmaxf(s, 0.f);
}

__global__ void theme2_k(const float* __restrict__ t1, const float* __restrict__ Wrs,
                         const float* __restrict__ brs, float* __restrict__ theme)
{
    int idx = blockIdx.x * blockDim.x + threadIdx.x;
    if (idx >= B * H) return;
    int b = idx / H, o = idx % H;
    float s = brs[o];
    const float* tv = t1 + (size_t)b * HS;
    for (int j = 0; j < HS; ++j) s += tv[j] * Wrs[(size_t)j * H + o];
    theme[idx] = 1.0f / (1.0f + expf(-s));
}

__global__ __launch_bounds__(256) void conv_split(
    const __hip_bfloat16* __restrict__ Ahk, const __hip_bfloat16* __restrict__ CWb,
    float* __restrict__ Pbuf)
{
    __shared__ __align__(16) unsigned short As2[128 * 64];
    __shared__ __align__(16) unsigned short Bs2[128 * 64];
    const int tid = threadIdx.x;
    const int wave = tid >> 6;
    const int wr = wave >> 1, wc = wave & 1;
    const int quad = (tid & 63) >> 4, m16 = tid & 15;
    const int n0 = blockIdx.x * 128, m0 = blockIdx.y * 128;
    const int ksb = blockIdx.z * (RC / KS);

    f32x4 acc[4][4] = {};
    for (int k0 = 0; k0 < RC / KS; k0 += 64) {
#pragma unroll
        for (int p = 0; p < 4; ++p) {
            int o = p * 4096 + tid * 16;
            int row = o >> 7, slot = (o >> 4) & 7;
            int kg = ksb + k0 + (slot ^ (row & 7)) * 8;
            gl_lds16((const unsigned short*)Ahk + (size_t)(m0 + row) * RC + kg, (char*)As2 + o);
            gl_lds16((const unsigned short*)CWb + (size_t)(n0 + row) * RC + kg, (char*)Bs2 + o);
        }
        __syncthreads();
#pragma unroll
        for (int c2 = 0; c2 < 2; ++c2) {
            const int k8 = c2 * 4 + quad;
            short8 av[4], bv[4];
#pragma unroll
            for (int i = 0; i < 4; ++i) {
                int arow = wr * 64 + i * 16 + m16;
                av[i] = *(const short8*)&As2[arow * 64 + (k8 ^ (arow & 7)) * 8];
            }
#pragma unroll
            for (int j = 0; j < 4; ++j) {
                int brow = wc * 64 + j * 16 + m16;
                bv[j] = *(const short8*)&Bs2[brow * 64 + (k8 ^ (brow & 7)) * 8];
            }
#pragma unroll
            for (int i = 0; i < 4; ++i)
#pragma unroll
                for (int j = 0; j < 4; ++j)
                    acc[i][j] = __builtin_amdgcn_mfma_f32_16x16x32_bf16(av[i], bv[j], acc[i][j], 0, 0, 0);
        }
        __syncthreads();
    }
    float* P = Pbuf + (size_t)blockIdx.z * B * H;
#pragma unroll
    for (int j = 0; j < 4; ++j) {
        const int col = n0 + wc * 64 + j * 16 + m16;
#pragma unroll
        for (int i = 0; i < 4; ++i) {
            const int rb = m0 + wr * 64 + i * 16 + quad * 4;
#pragma unroll
            for (int r = 0; r < 4; ++r)
                P[(size_t)(rb + r) * H + col] = acc[i][j][r];
        }
    }
}

__global__ void conv_reduce(const float* __restrict__ Pbuf, const float* __restrict__ conv_b,
                            const float* __restrict__ theme, float* __restrict__ out0)
{
    int i = blockIdx.x * blockDim.x + threadIdx.x;
    if (i >= B * H) return;
    float s = conv_b[i & (H - 1)];
#pragma unroll
    for (int ks = 0; ks < KS; ++ks) s += Pbuf[(size_t)ks * B * H + i];
    out0[i] = theme[i] * s;
}

} // namespace

extern "C" void kernel_launch(void* const* d_in, const int* in_sizes, int n_in,
                              void* d_out, int out_size, void* d_ws, size_t ws_size,
                              hipStream_t stream)
{
    (void)in_sizes; (void)n_in; (void)out_size; (void)ws_size;
    const float* x      = (const float*)d_in[0];
    const float* tme    = (const float*)d_in[1];
    const float* Wk     = (const float*)d_in[2];
    const float* bk     = (const float*)d_in[3];
    const float* Wr     = (const float*)d_in[4];
    const float* br     = (const float*)d_in[5];
    const float* Ws     = (const float*)d_in[6];
    const float* bs     = (const float*)d_in[7];
    const float* Wrs    = (const float*)d_in[8];
    const float* brs    = (const float*)d_in[9];
    const float* conv_w = (const float*)d_in[10];
    const float* conv_b = (const float*)d_in[11];

    float* out0 = (float*)d_out;
    float* dist_out = out0 + (size_t)B * H;

    // workspace carve (~163 MB)
    char* w = (char*)d_ws;
    __hip_bfloat16* WgT  = (__hip_bfloat16*)w; w += (size_t)16 * NROW * KIN * 2;
    __hip_bfloat16* xb   = (__hip_bfloat16*)w; w += (size_t)B * T * F * 2;
    __hip_bfloat16* CWb  = (__hip_bfloat16*)w; w += (size_t)H * RC * 2;
    __hip_bfloat16* Ahk  = (__hip_bfloat16*)w; w += (size_t)B * RC * 2;
    __hip_bfloat16* hb0  = (__hip_bfloat16*)w; w += (size_t)B * H * 2;
    __hip_bfloat16* hb1  = (__hip_bfloat16*)w; w += (size_t)B * H * 2;
    __hip_bfloat16* tmp_h = (__hip_bfloat16*)w; w += (size_t)KW * B * H * 2;
    float* biasg  = (float*)w; w += (size_t)NG * 4;
    float* wrowg  = (float*)w; w += (size_t)NG * 4;
    float* bias16 = (float*)w; w += 64;
    float* wrow16 = (float*)w; w += 64;
    float* tmp_ds = (float*)w; w += (size_t)KW * B * 4;
    float* mean_h = (float*)w; w += (size_t)B * H * 4;
    float* t1     = (float*)w; w += (size_t)B * HS * 4;
    float* theme  = (float*)w; w += (size_t)B * H * 4;
    float* Pbuf   = (float*)w; w += (size_t)KS * B * H * 4;
    float* tmeT   = (float*)w; w += (size_t)T * B * 4;
    unsigned* bar = (unsigned*)w; w += 4096;

    hipMemsetAsync(hb0, 0, (size_t)B * H * sizeof(__hip_bfloat16), stream);
    hipMemsetAsync(bar, 0, 4096, stream);

    prep_wgt<<<dim3(NG / 64, KIN / 64), 256, 0, stream>>>(Wk, Wr, WgT);
    prep_w16rep<<<(16 * 16 * KIN + 255) / 256, 256, 0, stream>>>(Wk, Wr, WgT);
    prep_small<<<1, 256, 0, stream>>>(Wk, bk, Wr, br, biasg, wrowg, bias16, wrow16);
    convert_x<<<((B * T * F / 4) + 255) / 256, 256, 0, stream>>>(x, xb);
    prep_convw<<<((H * RC / 4) + 255) / 256, 256, 0, stream>>>(conv_w, CWb);
    prep_tmet<<<dim3(B / 32, T / 32), 256, 0, stream>>>(tme, tmeT);

    {
        StepArgs sa;
        sa.xb = xb; sa.h0 = hb0; sa.h1 = hb1; sa.WgT = WgT;
        sa.biasg = biasg; sa.wrowg = wrowg; sa.bias16 = bias16; sa.wrow16 = wrow16;
        sa.tmeT = tmeT; sa.tmp_h = tmp_h; sa.tmp_ds = tmp_ds; sa.dist_out = dist_out;
        sa.bar = bar;
        persistent_step<<<256, 512, 0, stream>>>(sa);
    }

    post_local<<<B, 128, 0, stream>>>(tmp_h, tmp_ds, mean_h, Ahk);
    theme1_k<<<(B * HS + 255) / 256, 256, 0, stream>>>(mean_h, Ws, bs, t1);
    theme2_k<<<(B * H + 255) / 256, 256, 0, stream>>>(t1, Wrs, brs, theme);
    conv_split<<<dim3(H / 128, B / 128, KS), 256, 0, stream>>>(Ahk, CWb, Pbuf);
    conv_reduce<<<(B * H + 255) / 256, 256, 0, stream>>>(Pbuf, conv_b, theme, out0);
}